// Round 5
// baseline (333.181 us; speedup 1.0000x reference)
//
#include <hip/hip_runtime.h>
#include <hip/hip_bf16.h>
#include <math.h>

#define N_    8
#define CIN   32
#define COUT  32
#define AUX   128
#define HID   256
#define HWD   384
#define HW2   (HWD*HWD)
#define MODOUT (COUT*CIN*9)   // 9216

typedef short s8v  __attribute__((ext_vector_type(8)));   // 8 bf16 (4 VGPRs)
typedef float f16v __attribute__((ext_vector_type(16)));  // 32x32 C/D frag

__device__ __forceinline__ unsigned short f2b(float f) {  // fp32 -> bf16 RNE
    unsigned u = __float_as_uint(f);
    u += 0x7FFF + ((u >> 16) & 1);
    return (unsigned short)(u >> 16);
}
__device__ __forceinline__ unsigned pk2(float lo, float hi) { // v_cvt_pk_bf16_f32
    union { __hip_bfloat162 h; unsigned u; } cv;
    cv.h = __float22bfloat162_rn(make_float2(lo, hi));
    return cv.u;
}
__device__ __forceinline__ float prelu_f(float z, float a) { return z >= 0.f ? z : a * z; }

// ---------------- Kernel A: h, hb, bias (8 blocks) -------------------------
__global__ __launch_bounds__(256) void mlp_head(
    const float* __restrict__ y,
    const float* __restrict__ fc_w1, const float* __restrict__ fc_b1, const float* __restrict__ fc_a,
    const float* __restrict__ b_w1,  const float* __restrict__ b_b1,  const float* __restrict__ b_a,
    const float* __restrict__ b_w2,  const float* __restrict__ b_b2,
    float* __restrict__ ws_h, float* __restrict__ ws_bias)
{
    __shared__ float ly[AUX];
    __shared__ float lhb[HID];
    const int n = blockIdx.x;
    const int j = threadIdx.x;
    if (j < AUX) ly[j] = y[n*AUX + j];
    __syncthreads();
    float ha = fc_b1[j];
    float hb = b_b1[j];
    for (int k = 0; k < AUX; ++k) {
        const float yv = ly[k];
        ha += yv * fc_w1[k*HID + j];
        hb += yv * b_w1[k*HID + j];
    }
    ws_h[n*HID + j] = prelu_f(ha, fc_a[0]);
    lhb[j] = prelu_f(hb, b_a[0]);
    __syncthreads();
    if (j < COUT) {
        float acc = b_b2[j];
        for (int k = 0; k < HID; ++k) acc += lhb[k] * b_w2[k*COUT + j];
        ws_bias[n*COUT + j] = acc;
    }
}

// ------- Kernel B: modulated bf16 weights, K split 8 ways (288 blocks) -----
// out layout: wmod[n][tap][co][ci]  (ci contiguous -> A-frag dwordx4 loads)
__global__ __launch_bounds__(256) void mod_weights(
    const float* __restrict__ ws_h,
    const float* __restrict__ fc_w2, const float* __restrict__ fc_b2,
    const float* __restrict__ weight, unsigned short* __restrict__ wmod)
{
    __shared__ float lh[N_*HID];        // 8 KB
    __shared__ float red[8][32][N_];    // [jc][ml][n], 8 KB
    const int tid = threadIdx.x;
    for (int i = tid; i < N_*HID; i += 256) lh[i] = ws_h[i];
    __syncthreads();
    const int ml = tid & 31;
    const int jc = tid >> 5;
    const int m  = blockIdx.x * 32 + ml;
    float acc[N_];
#pragma unroll
    for (int n = 0; n < N_; ++n) acc[n] = 0.f;
    for (int jj = 0; jj < 32; ++jj) {
        const int j = jc*32 + jj;
        const float w = fc_w2[j*MODOUT + m];
#pragma unroll
        for (int n = 0; n < N_; ++n) acc[n] += lh[n*HID + j] * w;
    }
#pragma unroll
    for (int n = 0; n < N_; ++n) red[jc][ml][n] = acc[n];
    __syncthreads();
    const int nn = jc;                  // reuse thread as (ml, n)
    float s = fc_b2[m];
#pragma unroll
    for (int k = 0; k < 8; ++k) s += red[k][ml][nn];
    const float mod = 1.f / (1.f + __expf(-s));
    const float v = mod * weight[m];
    const int co = m / 288, r = m - co*288;
    const int ci = r / 9,  tap = r - ci*9;
    wmod[((nn*9 + tap)*COUT + co)*CIN + ci] = f2b(v);
}

// ---------------- Kernel C: conv as 9 shifted 1x1 GEMMs via MFMA -----------
// v6 = v5 pipeline (counted-vmcnt issue order cc0 -> a0 -> cc1; raw
// lgkm-only barrier 1 so cc1 HBM loads stay in flight and land under the
// cc0-half MFMAs; XOR-swizzled LDS; liveness-shaped acc/a1/bias; nontemporal
// epilogue stores) + XCD-chunked block swizzle: 2304 blocks = 8 XCD x 288,
// 288 = one full image n -> each XCD owns one image, so tile halos (1.41x
// read amplification) hit that XCD's L2 instead of HBM. Bijective since
// 2304 % 8 == 0 (m157/m204 rule).
#define TH    8
#define TCOL  64
#define LROWS 10
#define LCOLS 72
#define HALF  (LROWS*LCOLS*16)   // 11520 ushorts per cc half

__global__ __launch_bounds__(256, 2) void conv_mfma(
    const float* __restrict__ x,
    const unsigned short* __restrict__ wmod,
    const float* __restrict__ bias,
    float* __restrict__ out)
{
    __shared__ __align__(16) unsigned short lx[2*HALF];  // 46080 B

    const int tid = threadIdx.x;
    // ---- XCD-chunked swizzle: lid -> (n, ty, tx); XCD k gets image k ----
    const int lid = blockIdx.x + 6*blockIdx.y + 288*blockIdx.z;  // grid 6x48x8
    const int n   = lid & 7;           // new_lid = n*288 + pos
    const int pos = lid >> 3;
    const int ty  = pos / 6;
    const int tx  = pos - ty*6;
    const int gh  = ty * TH;
    const int gw  = tx * TCOL;

    const int lane = tid & 63;
    const int wv  = tid >> 6;     // wave 0..3
    const int lm  = lane & 31;    // co (A) / pixel (B,D) lane index
    const int h   = lane >> 5;    // k-oct selector

    // staging unit decode: unit u -> (o, row, q); 360 units per cc half
    const int o0 = tid & 1;
    const int rc0 = tid >> 1;
    const int row0 = rc0 / 18, q0 = rc0 - row0*18;
    const bool has1 = tid < 104;
    const int u1 = tid + 256;
    const int o1 = u1 & 1;
    const int rc1 = u1 >> 1;
    const int row1 = rc1 / 18, q1 = rc1 - row1*18;

    // -------- issue: global float4 loads for one unit (8 ci planes) --------
    auto issue = [&](int cc, int o, int row, int q, float4* v) {
        const int gr = gh + row - 1;
        const int gc = gw + q*4 - 4;
        if ((unsigned)gr < HWD && (unsigned)gc < HWD) {
            const float* xb = x + ((size_t)(n*CIN + cc*16 + o*8)*HWD + gr)*HWD + gc;
#pragma unroll
            for (int ci = 0; ci < 8; ++ci)
                v[ci] = *(const float4*)(xb + (size_t)ci*HW2);
        } else {
#pragma unroll
            for (int ci = 0; ci < 8; ++ci)
                v[ci] = make_float4(0.f, 0.f, 0.f, 0.f);
        }
    };

    // -------- convert + swizzled LDS write for one unit --------------------
    // idx = row*1152 + ((col*16 + o*8) ^ ((q&7)<<3)); bijective (XOR field =
    // bits 3..5 of the ushort index, a function of strictly-higher bits).
    auto cwrite = [&](int cc, int o, int row, int q, const float4* v) {
        const int base = cc*HALF + row*1152;           // 1152 = LCOLS*16
        const int xq = (q & 7) << 3;                   // XOR field (ushort units)
#pragma unroll
        for (int c = 0; c < 4; ++c) {
            const unsigned w0 = pk2(((const float*)&v[0])[c], ((const float*)&v[1])[c]);
            const unsigned w1 = pk2(((const float*)&v[2])[c], ((const float*)&v[3])[c]);
            const unsigned w2 = pk2(((const float*)&v[4])[c], ((const float*)&v[5])[c]);
            const unsigned w3 = pk2(((const float*)&v[6])[c], ((const float*)&v[7])[c]);
            const int idx = base + ((((q*4 + c)*16) + o*8) ^ xq);
            *(int4*)&lx[idx] = make_int4((int)w0, (int)w1, (int)w2, (int)w3);
        }
    };

    // -------- precomputed swizzled read column offsets (6 values) ----------
    int cswz[2][3];
#pragma unroll
    for (int cg = 0; cg < 2; ++cg)
#pragma unroll
        for (int kw = 0; kw < 3; ++kw) {
            const int colv = cg*32 + lm + 3 + kw;      // LDS col 0 == global gw-4
            cswz[cg][kw] = (colv*16 + h*8) ^ (((colv >> 2) & 7) << 3);
        }

    auto loadA = [&](int cc, s8v* a) {
#pragma unroll
        for (int t = 0; t < 9; ++t)
            a[t] = *(const s8v*)&wmod[(((n*9 + t)*COUT + lm)*CIN) + cc*16 + h*8];
    };

    f16v acc[4];

    auto compute = [&](int cc, const s8v* a) {
#pragma unroll
        for (int g = 0; g < 4; ++g) {
            const int rr = 2*wv + (g & 1);
            const int cg = g >> 1;
#pragma unroll
            for (int kh = 0; kh < 3; ++kh) {
                const int rbase = cc*HALF + (rr + kh)*1152;
#pragma unroll
                for (int kw = 0; kw < 3; ++kw) {
                    const s8v b = *(const s8v*)&lx[rbase + cswz[cg][kw]];
                    acc[g] = __builtin_amdgcn_mfma_f32_32x32x16_bf16(a[kh*3 + kw], b, acc[g], 0, 0, 0);
                }
            }
        }
    };

    // ---- issue phase: VMEM issue ORDER is the pipeline -------------------
    // group 1: cc0 x (HBM)   group 2: a0 (L2)   group 3: cc1 x (HBM)
    // sched_barrier(0) between groups pins the order so every downstream
    // wait is a counted vmcnt, never a drain.
    float4 v00[8], v01[8], v10[8], v11[8];
    s8v a0[9];
    issue(0, o0, row0, q0, v00);
    if (has1) issue(0, o1, row1, q1, v01);
    __builtin_amdgcn_sched_barrier(0);
    loadA(0, a0);
    __builtin_amdgcn_sched_barrier(0);
    issue(1, o0, row0, q0, v10);
    if (has1) issue(1, o1, row1, q1, v11);
    __builtin_amdgcn_sched_barrier(0);

    // ---- stage cc0: waits cc0 loads only (a0 + cc1 stay in flight) --------
    cwrite(0, o0, row0, q0, v00);
    if (has1) cwrite(0, o1, row1, q1, v01);

    // ---- barrier 1: RAW s_barrier, lgkmcnt only — cc1 loads NOT drained ---
    __builtin_amdgcn_sched_barrier(0);
    asm volatile("s_waitcnt lgkmcnt(0)" ::: "memory");
    __builtin_amdgcn_s_barrier();
    __builtin_amdgcn_sched_barrier(0);

    // acc init here (first use below) — keeps it out of staging-phase liveness
#pragma unroll
    for (int g = 0; g < 4; ++g)
#pragma unroll
        for (int r = 0; r < 16; ++r) acc[g][r] = 0.f;

    compute(0, a0);                    // waits a0 only (counted); cc1 lands here

    // ---- stage cc1; a1 + bias issued first (L2-hot, soak under converts) --
    s8v a1[9];
    loadA(1, a1);
    float4 b4[4];
#pragma unroll
    for (int i = 0; i < 4; ++i)
        b4[i] = *(const float4*)&bias[n*COUT + i*8 + 4*h];
    cwrite(1, o0, row0, q0, v10);      // waits cc1 x loads (latency hidden)
    if (has1) cwrite(1, o1, row1, q1, v11);
    __syncthreads();                   // buf1 ready (full drain is fine here)

    compute(1, a1);

    // ---- epilogue: bias + coalesced nontemporal dword stores --------------
    // out is write-once/never-re-read: nt stores keep x resident in L2/L3.
#pragma unroll
    for (int g = 0; g < 4; ++g) {
        const int rr = 2*wv + (g & 1);
        const int cg = g >> 1;
        float* ob = out + (size_t)(n*COUT)*HW2 + (size_t)(gh + rr)*HWD + gw + cg*32 + lm;
#pragma unroll
        for (int r = 0; r < 16; ++r) {
            const float brv = ((const float*)&b4[r >> 2])[r & 3];  // co=(r&3)+8*(r>>2)+4h
            const int co = (r & 3) + 8*(r >> 2) + 4*h;
            __builtin_nontemporal_store(acc[g][r] + brv, &ob[(size_t)co*HW2]);
        }
    }
}

extern "C" void kernel_launch(void* const* d_in, const int* in_sizes, int n_in,
                              void* d_out, int out_size, void* d_ws, size_t ws_size,
                              hipStream_t stream) {
    const float* x     = (const float*)d_in[0];
    const float* y     = (const float*)d_in[1];
    const float* weight= (const float*)d_in[2];
    const float* fc_w1 = (const float*)d_in[3];
    const float* fc_b1 = (const float*)d_in[4];
    const float* fc_a  = (const float*)d_in[5];
    const float* fc_w2 = (const float*)d_in[6];
    const float* fc_b2 = (const float*)d_in[7];
    const float* b_w1  = (const float*)d_in[8];
    const float* b_b1  = (const float*)d_in[9];
    const float* b_a   = (const float*)d_in[10];
    const float* b_w2  = (const float*)d_in[11];
    const float* b_b2  = (const float*)d_in[12];
    float* out = (float*)d_out;

    unsigned short* ws_wmod = (unsigned short*)d_ws;                 // 147456 B
    float* ws_h    = (float*)((char*)d_ws + (size_t)MODOUT*N_*2);    // 2048 f
    float* ws_bias = ws_h + N_*HID;                                  // 256 f

    mlp_head<<<N_, 256, 0, stream>>>(y, fc_w1, fc_b1, fc_a, b_w1, b_b1, b_a,
                                     b_w2, b_b2, ws_h, ws_bias);
    mod_weights<<<MODOUT/32, 256, 0, stream>>>(ws_h, fc_w2, fc_b2, weight, ws_wmod);
    conv_mfma<<<dim3(HWD/TCOL, HWD/TH, N_), 256, 0, stream>>>(x, ws_wmod, ws_bias, out);
}